// Round 3
// baseline (131.741 us; speedup 1.0000x reference)
//
#include <hip/hip_runtime.h>
#include <cmath>

// PillarFeatureNet fused: augment(10ch) -> linear(64) -> BN(inference) -> exact GELU -> max over points.
// Key algebra: y[m][o] = f0*A0 + f1*A1 + f2*A2 + f3*A3 + C_pillar  (4 FMAs/point instead of 10 MACs)
// GELU is valley-shaped => max_m gelu(y_m) = max(gelu(max_m y), gelu(min_m y)): 2 erfs per (n,o).
// Masked points contribute y = b (BN of 0), added once when num_points < 32.
// points_mean sums ALL 32 rows (reference semantics), mask applies only to the matmul.
//
// R3 (VALU-pipe saturated per rocprof: VALUBusy 93-96%, HBM 11-15%, conflicts 0):
//   - v_pk_fma_f32 inner loop: 4 packed FMAs per 2 points instead of 8 scalar FMAs.
//     We are VALU-ISSUE bound, not flop-bound: packed fp32 halves instructions at same flops.
//   - LDS tile switched to SoA [x(32)|y(32)|z(32)|w(32)] per pillar so (x0,x1) etc. are
//     adjacent 8B pairs: writes hit all 32 banks (free 2-way for wave64), reads are 8B
//     broadcasts (ds_read2_b64-mergeable), both conflict-free.
//   - shuffle reduction x/y packed via v_pk_add_f32 (z stays scalar).

typedef float f32x2 __attribute__((ext_vector_type(2)));

__device__ __forceinline__ float gelu_exact(float x) {
    return 0.5f * x * (1.0f + erff(x * 0.70710678118654752440f));
}

__device__ __forceinline__ float max3f(float a, float b, float c) {
    float d;
    asm("v_max3_f32 %0, %1, %2, %3" : "=v"(d) : "v"(a), "v"(b), "v"(c));
    return d;
}
__device__ __forceinline__ float min3f(float a, float b, float c) {
    float d;
    asm("v_min3_f32 %0, %1, %2, %3" : "=v"(d) : "v"(a), "v"(b), "v"(c));
    return d;
}
__device__ __forceinline__ f32x2 pk_fma(f32x2 a, f32x2 b, f32x2 c) {
    f32x2 d;
    asm("v_pk_fma_f32 %0, %1, %2, %3" : "=v"(d) : "v"(a), "v"(b), "v"(c));
    return d;
}
__device__ __forceinline__ f32x2 pk_add(f32x2 a, f32x2 b) {
    f32x2 d;
    asm("v_pk_add_f32 %0, %1, %2" : "=v"(d) : "v"(a), "v"(b));
    return d;
}
__device__ __forceinline__ f32x2 shfl_xor2(f32x2 v, int m) {
    double d = __builtin_bit_cast(double, v);
    d = __shfl_xor(d, m);
    return __builtin_bit_cast(f32x2, d);
}

__global__ __launch_bounds__(256) void pfn_kernel(
    const float* __restrict__ features,   // (N, 32, 4)
    const int*   __restrict__ num_points, // (N,)
    const int*   __restrict__ coors,      // (N, 4)
    const float* __restrict__ W,          // (64, 10)
    const float* __restrict__ gamma,      // (64,)
    const float* __restrict__ beta,       // (64,)
    const float* __restrict__ rmean,      // (64,)
    const float* __restrict__ rvar,       // (64,)
    float*       __restrict__ out,        // (N, 64)
    int nTotal)
{
    // per-wave 1KB slot, SoA per pillar: [x(32)|y(32)|z(32)|w(32)], pillar B at +128 floats
    __shared__ float ldsf[4][256];

    const int lane = threadIdx.x & 63;
    const int wid  = threadIdx.x >> 6;
    const int waveGlobal = blockIdx.x * 4 + wid;
    const int waveCount  = gridDim.x * 4;
    const int nPairs = (nTotal + 1) >> 1;

    // lane == output channel o
    const int o = lane;
    const float w0 = W[o*10+0], w1 = W[o*10+1], w2 = W[o*10+2], w3 = W[o*10+3],
                w4 = W[o*10+4], w5 = W[o*10+5], w6 = W[o*10+6], w7 = W[o*10+7],
                w8 = W[o*10+8], w9 = W[o*10+9];
    const float a = gamma[o] / sqrtf(rvar[o] + 1e-3f);        // inv_std * gamma
    const float b = fmaf(-rmean[o], a, beta[o]);              // BN(0) value
    const float A0 = a*(w0+w4+w7), A1 = a*(w1+w5+w8), A2 = a*(w2+w6+w9), A3 = a*w3;
    const f32x2 A0p = {A0, A0}, A1p = {A1, A1}, A2p = {A2, A2}, A3p = {A3, A3};

    float* slot = ldsf[wid];

    // packed dot+minmax scan over one pillar's SoA column (broadcast reads)
    auto scan = [&](const float* col, int n, float C, float& vmax_, float& vmin_) {
        const f32x2 Cp = {C, C};
        const int pairs = (n + 1) >> 1;   // n >= 1 always
        #pragma unroll 2
        for (int q = 0; q < pairs - 1; ++q) {
            f32x2 xp = *reinterpret_cast<const f32x2*>(col      + 2*q);
            f32x2 yp = *reinterpret_cast<const f32x2*>(col + 32 + 2*q);
            f32x2 zp = *reinterpret_cast<const f32x2*>(col + 64 + 2*q);
            f32x2 wp = *reinterpret_cast<const f32x2*>(col + 96 + 2*q);
            f32x2 acc = pk_fma(xp, A0p, Cp);
            acc = pk_fma(yp, A1p, acc);
            acc = pk_fma(zp, A2p, acc);
            acc = pk_fma(wp, A3p, acc);
            vmax_ = max3f(vmax_, acc.x, acc.y);
            vmin_ = min3f(vmin_, acc.x, acc.y);
        }
        {   // last pair: second element valid only when n is even
            const int q = pairs - 1;
            f32x2 xp = *reinterpret_cast<const f32x2*>(col      + 2*q);
            f32x2 yp = *reinterpret_cast<const f32x2*>(col + 32 + 2*q);
            f32x2 zp = *reinterpret_cast<const f32x2*>(col + 64 + 2*q);
            f32x2 wp = *reinterpret_cast<const f32x2*>(col + 96 + 2*q);
            f32x2 acc = pk_fma(xp, A0p, Cp);
            acc = pk_fma(yp, A1p, acc);
            acc = pk_fma(zp, A2p, acc);
            acc = pk_fma(wp, A3p, acc);
            if (n & 1) {
                vmax_ = fmaxf(vmax_, acc.x);
                vmin_ = fminf(vmin_, acc.x);
            } else {
                vmax_ = max3f(vmax_, acc.x, acc.y);
                vmin_ = min3f(vmin_, acc.x, acc.y);
            }
        }
    };

    for (int p = waveGlobal; p < nPairs; p += waveCount) {
        const int iA = 2*p;
        const bool hasB = (2*p + 1 < nTotal);
        const int iB = hasB ? (2*p + 1) : (nTotal - 1);

        // ---- phase 1: coalesced load of 2 pillars (1 KB contiguous), SoA store, mean reduce ----
        const float4* fb = reinterpret_cast<const float4*>(features) + (size_t)p * 64;
        float4 f = fb[lane];          // lane l -> pillar (2p + (l>=32)), point (l&31)

        const int sbase = (lane >> 5) * 128 + (lane & 31);  // pillar*128 + point
        slot[sbase]      = f.x;       // banks = point%32: all 32 banks, free 2-way
        slot[sbase + 32] = f.y;
        slot[sbase + 64] = f.z;
        slot[sbase + 96] = f.w;

        f32x2 sxy = {f.x, f.y};
        float sz = f.z;
        #pragma unroll
        for (int d = 1; d < 32; d <<= 1) {
            sxy = pk_add(sxy, shfl_xor2(sxy, d));
            sz += __shfl_xor(sz, d);
        }
        const f32x2 txy = shfl_xor2(sxy, 32);
        const float tz  = __shfl_xor(sz, 32);
        const bool lo = (lane < 32);
        const float sAx = lo ? sxy.x : txy.x, sAy = lo ? sxy.y : txy.y, sAz = lo ? sz : tz;
        const float sBx = lo ? txy.x : sxy.x, sBy = lo ? txy.y : sxy.y, sBz = lo ? tz : sz;

        const int nA = num_points[iA];
        const int nB = num_points[iB];
        const int4 cA = reinterpret_cast<const int4*>(coors)[iA];
        const int4 cB = reinterpret_cast<const int4*>(coors)[iB];

        // points_mean = sum(all 32) * rcp(num_points); v_rcp_f32 <=1ulp, ~1e-6 downstream err
        const float rcA = __builtin_amdgcn_rcpf((float)nA);
        const float rcB = __builtin_amdgcn_rcpf((float)nB);
        const float mAx = sAx * rcA, mAy = sAy * rcA, mAz = sAz * rcA;
        const float mBx = sBx * rcB, mBy = sBy * rcB, mBz = sBz * rcB;

        // voxel-center offsets: cx=coors[:,2], cy=coors[:,1], cz=coors[:,0]
        const float ccxA = fmaf((float)cA.z, 0.2f,   0.1f);
        const float ccyA = fmaf((float)cA.y, 0.2f, -39.9f);
        const float cczA = fmaf((float)cA.x, 4.0f,  -1.0f);
        const float ccxB = fmaf((float)cB.z, 0.2f,   0.1f);
        const float ccyB = fmaf((float)cB.y, 0.2f, -39.9f);
        const float cczB = fmaf((float)cB.x, 4.0f,  -1.0f);

        const float KA = -(mAx*w4 + mAy*w5 + mAz*w6 + ccxA*w7 + ccyA*w8 + cczA*w9);
        const float KB = -(mBx*w4 + mBy*w5 + mBz*w6 + ccxB*w7 + ccyB*w8 + cczB*w9);
        const float CA = fmaf(a, KA, b);
        const float CB = fmaf(a, KB, b);

        // intra-wave LDS RAW: DS ops are in-order per wave; fence the compiler + drain lgkm
        __asm__ volatile("s_waitcnt lgkmcnt(0)" ::: "memory");

        // ---- phase 2: packed per-channel dot + minmax ----
        float vmaxA = -INFINITY, vminA = INFINITY;
        scan(slot,       nA, CA, vmaxA, vminA);
        float vmaxB = -INFINITY, vminB = INFINITY;
        scan(slot + 128, nB, CB, vmaxB, vminB);

        if (nA < 32) { vmaxA = fmaxf(vmaxA, b); vminA = fminf(vminA, b); }
        if (nB < 32) { vmaxB = fmaxf(vmaxB, b); vminB = fminf(vminB, b); }

        // valley property: max over set attained at min or max pre-activation
        const float rAo = fmaxf(gelu_exact(vmaxA), gelu_exact(vminA));
        const float rBo = fmaxf(gelu_exact(vmaxB), gelu_exact(vminB));

        out[(size_t)iA * 64 + o] = rAo;
        if (hasB) out[(size_t)iB * 64 + o] = rBo;
    }
}

extern "C" void kernel_launch(void* const* d_in, const int* in_sizes, int n_in,
                              void* d_out, int out_size, void* d_ws, size_t ws_size,
                              hipStream_t stream) {
    const float* features   = (const float*)d_in[0];
    const int*   num_points = (const int*)  d_in[1];
    const int*   coors      = (const int*)  d_in[2];
    const float* W          = (const float*)d_in[3];
    const float* gamma      = (const float*)d_in[4];
    const float* beta       = (const float*)d_in[5];
    const float* rmean      = (const float*)d_in[6];
    const float* rvar       = (const float*)d_in[7];
    float* out = (float*)d_out;

    const int nTotal = in_sizes[1];  // N pillars

    // 2 pairs per wave: fine-grained blocks let the HW scheduler backfill (tail balance).
    const int nPairs = (nTotal + 1) / 2;
    int blocks = (nPairs + 7) / 8;   // 4 waves/block x 2 pairs/wave
    if (blocks < 1) blocks = 1;
    pfn_kernel<<<blocks, 256, 0, stream>>>(features, num_points, coors, W,
                                           gamma, beta, rmean, rvar, out, nTotal);
}

// Round 4
// 123.471 us; speedup vs baseline: 1.0670x; 1.0670x over previous
//
#include <hip/hip_runtime.h>
#include <cmath>

// PillarFeatureNet fused: augment(10ch) -> linear(64) -> BN(inference) -> exact GELU -> max over points.
// Key algebra: y[m][o] = f0*A0 + f1*A1 + f2*A2 + f3*A3 + C_pillar  (4 FMAs/point instead of 10 MACs)
// GELU is valley-shaped => max_m gelu(y_m) = max(gelu(max_m y), gelu(min_m y)): 2 gelus per (n,o).
// Masked points contribute y = b (BN of 0), merged once when num_points < 32.
// points_mean sums ALL 32 rows (reference semantics), mask applies only to the matmul.
//
// R4 (R3 post-mortem: pk-packed scan lowered VALU count but added serial-chain stalls ->
//     REVERT scan to R2's proven AoS/scalar-fma form, 93% VALUBusy @ 43us):
//   - replace 4x ocml erff (branchy, both paths execute) with branchless A&S 7.1.26 erf,
//     evaluated PACKED: both gelu args of a pillar in one f32x2 via v_pk_fma_f32.
//     ~15 VALU slots per gelu-PAIR vs ~25-40 per single ocml erff.
//     |erf err| <= 1.5e-7 abs -> gelu err ~2e-6 abs (same order as accepted rcp change).
//     Signs folded into negated coefficients; asymptotics exact via exp underflow.

typedef float f32x2 __attribute__((ext_vector_type(2)));

__device__ __forceinline__ float max3f(float a, float b, float c) {
    float d;
    asm("v_max3_f32 %0, %1, %2, %3" : "=v"(d) : "v"(a), "v"(b), "v"(c));
    return d;
}
__device__ __forceinline__ float min3f(float a, float b, float c) {
    float d;
    asm("v_min3_f32 %0, %1, %2, %3" : "=v"(d) : "v"(a), "v"(b), "v"(c));
    return d;
}
__device__ __forceinline__ f32x2 pk_fma(f32x2 a, f32x2 b, f32x2 c) {
    f32x2 d;
    asm("v_pk_fma_f32 %0, %1, %2, %3" : "=v"(d) : "v"(a), "v"(b), "v"(c));
    return d;
}
__device__ __forceinline__ f32x2 pk_mul(f32x2 a, f32x2 b) {
    f32x2 d;
    asm("v_pk_mul_f32 %0, %1, %2" : "=v"(d) : "v"(a), "v"(b));
    return d;
}
__device__ __forceinline__ float fast_exp2(float a) {
    float d;
    asm("v_exp_f32 %0, %1" : "=v"(d) : "v"(a));
    return d;
}

// Packed exact-GELU for 2 values (A&S 7.1.26 erf, branchless).
// gelu(x) = 0.5x + 0.5|x|*E(|x|/sqrt2), E = 1 - poly(s)*exp(-t^2), s = 1/(1+pt).
__device__ __forceinline__ f32x2 gelu2(f32x2 x) {
    const f32x2 c_t    = {0.70710678f, 0.70710678f};    // 1/sqrt2
    const f32x2 c_p    = {0.3275911f, 0.3275911f};
    const f32x2 c_one  = {1.0f, 1.0f};
    const f32x2 c_half = {0.5f, 0.5f};
    // negated A&S coefficients (folds the "1 - poly*e" sign for free)
    const f32x2 b1 = {-0.254829592f, -0.254829592f};
    const f32x2 b2 = { 0.284496736f,  0.284496736f};
    const f32x2 b3 = {-1.421413741f, -1.421413741f};
    const f32x2 b4 = { 1.453152027f,  1.453152027f};
    const f32x2 b5 = {-1.061405429f, -1.061405429f};
    // arg = -t^2*log2(e) = t * (ax * k), k = -0.72134752/0.70710678
    const f32x2 c_k = {-1.02013963f, -1.02013963f};

    f32x2 ax = {fabsf(x.x), fabsf(x.y)};
    f32x2 t  = pk_mul(ax, c_t);
    f32x2 u  = pk_fma(t, c_p, c_one);
    f32x2 s  = {__builtin_amdgcn_rcpf(u.x), __builtin_amdgcn_rcpf(u.y)};
    f32x2 poly = pk_fma(b5, s, b4);
    poly = pk_fma(poly, s, b3);
    poly = pk_fma(poly, s, b2);
    poly = pk_fma(poly, s, b1);
    poly = pk_mul(poly, s);                              // poly = -(a1 s + ... + a5 s^5)
    f32x2 t3  = pk_mul(ax, c_k);
    f32x2 arg = pk_mul(t, t3);                           // -t^2 * log2(e)
    f32x2 e   = {fast_exp2(arg.x), fast_exp2(arg.y)};
    f32x2 E   = pk_fma(poly, e, c_one);                  // 1 - a-poly*e
    f32x2 h   = pk_mul(x, c_half);
    f32x2 hax = pk_mul(ax, c_half);
    return pk_fma(hax, E, h);                            // 0.5x + 0.5|x|E
}

__global__ __launch_bounds__(256) void pfn_kernel(
    const float* __restrict__ features,   // (N, 32, 4)
    const int*   __restrict__ num_points, // (N,)
    const int*   __restrict__ coors,      // (N, 4)
    const float* __restrict__ W,          // (64, 10)
    const float* __restrict__ gamma,      // (64,)
    const float* __restrict__ beta,       // (64,)
    const float* __restrict__ rmean,      // (64,)
    const float* __restrict__ rvar,       // (64,)
    float*       __restrict__ out,        // (N, 64)
    int nTotal)
{
    __shared__ float4 lds[4][64];  // per-wave slot: [0..31] = pillar A points, [32..63] = pillar B

    const int lane = threadIdx.x & 63;
    const int wid  = threadIdx.x >> 6;
    const int waveGlobal = blockIdx.x * 4 + wid;
    const int waveCount  = gridDim.x * 4;
    const int nPairs = (nTotal + 1) >> 1;

    // lane == output channel o
    const int o = lane;
    const float w0 = W[o*10+0], w1 = W[o*10+1], w2 = W[o*10+2], w3 = W[o*10+3],
                w4 = W[o*10+4], w5 = W[o*10+5], w6 = W[o*10+6], w7 = W[o*10+7],
                w8 = W[o*10+8], w9 = W[o*10+9];
    const float a = gamma[o] / sqrtf(rvar[o] + 1e-3f);        // inv_std * gamma
    const float b = fmaf(-rmean[o], a, beta[o]);              // BN(0) value
    const float A0 = a*(w0+w4+w7), A1 = a*(w1+w5+w8), A2 = a*(w2+w6+w9), A3 = a*w3;

    for (int p = waveGlobal; p < nPairs; p += waveCount) {
        const int iA = 2*p;
        const bool hasB = (2*p + 1 < nTotal);
        const int iB = hasB ? (2*p + 1) : (nTotal - 1);

        // ---- phase 1: coalesced load of 2 pillars (1 KB contiguous), mean reduction ----
        const float4* fb = reinterpret_cast<const float4*>(features) + (size_t)p * 64;
        float4 f = fb[lane];          // lane l -> pillar (2p + (l>=32)), point (l&31)
        lds[wid][lane] = f;

        float sx = f.x, sy = f.y, sz = f.z;
        #pragma unroll
        for (int d = 1; d < 32; d <<= 1) {
            sx += __shfl_xor(sx, d);
            sy += __shfl_xor(sy, d);
            sz += __shfl_xor(sz, d);
        }
        const float tx = __shfl_xor(sx, 32), ty = __shfl_xor(sy, 32), tz = __shfl_xor(sz, 32);
        const bool lo = (lane < 32);
        const float sAx = lo ? sx : tx, sAy = lo ? sy : ty, sAz = lo ? sz : tz;
        const float sBx = lo ? tx : sx, sBy = lo ? ty : sy, sBz = lo ? tz : sz;

        const int nA = num_points[iA];
        const int nB = num_points[iB];
        const int4 cA = reinterpret_cast<const int4*>(coors)[iA];
        const int4 cB = reinterpret_cast<const int4*>(coors)[iB];

        // points_mean = sum(all 32) * rcp(num_points); v_rcp_f32 <=1ulp, ~1e-6 downstream err
        const float rcA = __builtin_amdgcn_rcpf((float)nA);
        const float rcB = __builtin_amdgcn_rcpf((float)nB);
        const float mAx = sAx * rcA, mAy = sAy * rcA, mAz = sAz * rcA;
        const float mBx = sBx * rcB, mBy = sBy * rcB, mBz = sBz * rcB;

        // voxel-center offsets: cx=coors[:,2], cy=coors[:,1], cz=coors[:,0]
        const float ccxA = fmaf((float)cA.z, 0.2f,   0.1f);
        const float ccyA = fmaf((float)cA.y, 0.2f, -39.9f);
        const float cczA = fmaf((float)cA.x, 4.0f,  -1.0f);
        const float ccxB = fmaf((float)cB.z, 0.2f,   0.1f);
        const float ccyB = fmaf((float)cB.y, 0.2f, -39.9f);
        const float cczB = fmaf((float)cB.x, 4.0f,  -1.0f);

        const float KA = -(mAx*w4 + mAy*w5 + mAz*w6 + ccxA*w7 + ccyA*w8 + cczA*w9);
        const float KB = -(mBx*w4 + mBy*w5 + mBz*w6 + ccxB*w7 + ccyB*w8 + cczB*w9);
        const float CA = fmaf(a, KA, b);
        const float CB = fmaf(a, KB, b);

        // intra-wave LDS RAW: DS ops are in-order per wave; fence the compiler + drain lgkm
        __asm__ volatile("s_waitcnt lgkmcnt(0)" ::: "memory");

        // ---- phase 2: per-channel dot + BN via 4 FMAs, 2-wide with v_max3/v_min3 ----
        float vmaxA = -INFINITY, vminA = INFINITY;
        {
            const float4* la = &lds[wid][0];
            int m = 0;
            for (; m + 2 <= nA; m += 2) {
                float4 t0 = la[m];      // broadcast reads: all lanes same address, no conflict
                float4 t1 = la[m+1];
                float y0 = fmaf(t0.x, A0, fmaf(t0.y, A1, fmaf(t0.z, A2, fmaf(t0.w, A3, CA))));
                float y1 = fmaf(t1.x, A0, fmaf(t1.y, A1, fmaf(t1.z, A2, fmaf(t1.w, A3, CA))));
                vmaxA = max3f(vmaxA, y0, y1);
                vminA = min3f(vminA, y0, y1);
            }
            if (m < nA) {
                float4 t = la[m];
                float y = fmaf(t.x, A0, fmaf(t.y, A1, fmaf(t.z, A2, fmaf(t.w, A3, CA))));
                vmaxA = fmaxf(vmaxA, y);
                vminA = fminf(vminA, y);
            }
        }
        float vmaxB = -INFINITY, vminB = INFINITY;
        {
            const float4* lb = &lds[wid][32];
            int m = 0;
            for (; m + 2 <= nB; m += 2) {
                float4 t0 = lb[m];
                float4 t1 = lb[m+1];
                float y0 = fmaf(t0.x, A0, fmaf(t0.y, A1, fmaf(t0.z, A2, fmaf(t0.w, A3, CB))));
                float y1 = fmaf(t1.x, A0, fmaf(t1.y, A1, fmaf(t1.z, A2, fmaf(t1.w, A3, CB))));
                vmaxB = max3f(vmaxB, y0, y1);
                vminB = min3f(vminB, y0, y1);
            }
            if (m < nB) {
                float4 t = lb[m];
                float y = fmaf(t.x, A0, fmaf(t.y, A1, fmaf(t.z, A2, fmaf(t.w, A3, CB))));
                vmaxB = fmaxf(vmaxB, y);
                vminB = fminf(vminB, y);
            }
        }
        if (nA < 32) { vmaxA = fmaxf(vmaxA, b); vminA = fminf(vminA, b); }
        if (nB < 32) { vmaxB = fmaxf(vmaxB, b); vminB = fminf(vminB, b); }

        // valley property: max over set attained at min or max pre-activation.
        // Packed branchless gelu: one f32x2 eval per pillar.
        const f32x2 gA = gelu2((f32x2){vmaxA, vminA});
        const f32x2 gB = gelu2((f32x2){vmaxB, vminB});
        const float rAo = fmaxf(gA.x, gA.y);
        const float rBo = fmaxf(gB.x, gB.y);

        out[(size_t)iA * 64 + o] = rAo;
        if (hasB) out[(size_t)iB * 64 + o] = rBo;
    }
}

extern "C" void kernel_launch(void* const* d_in, const int* in_sizes, int n_in,
                              void* d_out, int out_size, void* d_ws, size_t ws_size,
                              hipStream_t stream) {
    const float* features   = (const float*)d_in[0];
    const int*   num_points = (const int*)  d_in[1];
    const int*   coors      = (const int*)  d_in[2];
    const float* W          = (const float*)d_in[3];
    const float* gamma      = (const float*)d_in[4];
    const float* beta       = (const float*)d_in[5];
    const float* rmean      = (const float*)d_in[6];
    const float* rvar       = (const float*)d_in[7];
    float* out = (float*)d_out;

    const int nTotal = in_sizes[1];  // N pillars

    // 2 pairs per wave: fine-grained blocks let the HW scheduler backfill (tail balance).
    const int nPairs = (nTotal + 1) / 2;
    int blocks = (nPairs + 7) / 8;   // 4 waves/block x 2 pairs/wave
    if (blocks < 1) blocks = 1;
    pfn_kernel<<<blocks, 256, 0, stream>>>(features, num_points, coors, W,
                                           gamma, beta, rmean, rvar, out, nTotal);
}

// Round 6
// 121.639 us; speedup vs baseline: 1.0830x; 1.0151x over previous
//
#include <hip/hip_runtime.h>
#include <cmath>

// PillarFeatureNet fused: augment(10ch) -> linear(64) -> BN(inference) -> exact GELU -> max over points.
// Key algebra: y[m][o] = f0*A0 + f1*A1 + f2*A2 + f3*A3 + C_pillar  (4 FMAs/point)
// GELU valley-shaped => max_m gelu(y_m) = max(gelu(max y), gelu(min y)): 2 gelus per (n,o).
// Masked points contribute y = b (BN of 0), merged once when num_points < 32.
// points_mean sums ALL 32 rows (reference semantics), mask applies only to the matmul.
//
// R6 == R5 with the DPP builtin's ctrl/row_mask moved to template parameters
// (must be integer constant expressions; R5 passed them as runtime args -> compile error).
// R5 rationale (R4 post-mortem: VALUBusy fell 93->77% with little wall gain -> STALL-bound):
//   - C-DEFERRAL: scan tracks min/max of the dot part only; C added after. The mean/C chain
//     is off the critical path -> scan starts right after the LDS write.
//   - DPP reduction (row_shr 1/2/4/8 + row_bcast15 + readlane) replaces 15 serial DS shuffles:
//     pure VALU, ~70cyc chain vs ~250, frees the DS pipe for scan reads.
//   - dual-pair straight-line waves: both 1KB feature loads issued up front; 2nd load's
//     latency hides under 1st pair's compute; doubled ILP everywhere.
//   - scan depth-1 preload (padded LDS, safe over-read) to cover LDS read latency.
//   - drop lgkmcnt(0) hard drain (same-wave LDS RAW is in-order on DS pipe; compiler fence only).

typedef float f32x2 __attribute__((ext_vector_type(2)));

__device__ __forceinline__ float max3f(float a, float b, float c) {
    float d;
    asm("v_max3_f32 %0, %1, %2, %3" : "=v"(d) : "v"(a), "v"(b), "v"(c));
    return d;
}
__device__ __forceinline__ float min3f(float a, float b, float c) {
    float d;
    asm("v_min3_f32 %0, %1, %2, %3" : "=v"(d) : "v"(a), "v"(b), "v"(c));
    return d;
}
__device__ __forceinline__ f32x2 pk_fma(f32x2 a, f32x2 b, f32x2 c) {
    f32x2 d;
    asm("v_pk_fma_f32 %0, %1, %2, %3" : "=v"(d) : "v"(a), "v"(b), "v"(c));
    return d;
}
__device__ __forceinline__ f32x2 pk_mul(f32x2 a, f32x2 b) {
    f32x2 d;
    asm("v_pk_mul_f32 %0, %1, %2" : "=v"(d) : "v"(a), "v"(b));
    return d;
}
__device__ __forceinline__ float fast_exp2(float a) {
    float d;
    asm("v_exp_f32 %0, %1" : "=v"(d) : "v"(a));
    return d;
}

// Packed exact-GELU for 2 values (A&S 7.1.26 erf, branchless). |err| ~2e-6 abs.
__device__ __forceinline__ f32x2 gelu2(f32x2 x) {
    const f32x2 c_t    = {0.70710678f, 0.70710678f};
    const f32x2 c_p    = {0.3275911f, 0.3275911f};
    const f32x2 c_one  = {1.0f, 1.0f};
    const f32x2 b1 = {-0.254829592f, -0.254829592f};
    const f32x2 b2 = { 0.284496736f,  0.284496736f};
    const f32x2 b3 = {-1.421413741f, -1.421413741f};
    const f32x2 b4 = { 1.453152027f,  1.453152027f};
    const f32x2 b5 = {-1.061405429f, -1.061405429f};
    const f32x2 c_k = {-1.02013963f, -1.02013963f};   // arg = -t^2*log2(e)

    f32x2 ax = {fabsf(x.x), fabsf(x.y)};
    f32x2 t  = pk_mul(ax, c_t);
    f32x2 u  = pk_fma(t, c_p, c_one);
    f32x2 s  = {__builtin_amdgcn_rcpf(u.x), __builtin_amdgcn_rcpf(u.y)};
    f32x2 poly = pk_fma(b5, s, b4);
    poly = pk_fma(poly, s, b3);
    poly = pk_fma(poly, s, b2);
    poly = pk_fma(poly, s, b1);
    poly = pk_mul(poly, s);
    f32x2 t3  = pk_mul(ax, c_k);
    f32x2 arg = pk_mul(t, t3);
    f32x2 e   = {fast_exp2(arg.x), fast_exp2(arg.y)};
    f32x2 E   = pk_fma(poly, e, c_one);
    f32x2 h   = pk_mul(x, (f32x2){0.5f, 0.5f});
    f32x2 hax = pk_mul(ax, (f32x2){0.5f, 0.5f});
    return pk_fma(hax, E, h);
}

// DPP half-wave sums: returns sum(lanes 0..31) and sum(lanes 32..63). Pure VALU (no DS pipe).
// ctrl/row_mask must be integer constant expressions -> template parameters.
template <int CTRL, int ROW_MASK>
__device__ __forceinline__ float dpp_add(float v) {
    int x = __builtin_amdgcn_update_dpp(0, __builtin_bit_cast(int, v), CTRL, ROW_MASK, 0xf, false);
    return v + __builtin_bit_cast(float, x);
}
__device__ __forceinline__ void half_sums(float v, float& sA, float& sB) {
    v = dpp_add<0x111, 0xf>(v);   // row_shr:1
    v = dpp_add<0x112, 0xf>(v);   // row_shr:2
    v = dpp_add<0x114, 0xf>(v);   // row_shr:4
    v = dpp_add<0x118, 0xf>(v);   // row_shr:8  -> lane15/31/47/63 hold 16-lane sums
    v = dpp_add<0x142, 0xa>(v);   // row_bcast:15 into rows 1,3 -> lane31/63 hold 32-lane sums
    sA = __builtin_bit_cast(float, __builtin_amdgcn_readlane(__builtin_bit_cast(int, v), 31));
    sB = __builtin_bit_cast(float, __builtin_amdgcn_readlane(__builtin_bit_cast(int, v), 63));
}

// C-deferred scan: min/max of dot(f, A) over points [0,n); depth-1 preload (safe over-read
// into padded LDS). n is wave-uniform -> no divergence.
__device__ __forceinline__ void scan_minmax(const float4* base, int n,
                                            float A0, float A1, float A2, float A3,
                                            float& dmax, float& dmin) {
    float vmax = -INFINITY, vmin = INFINITY;
    float4 t0 = base[0], t1 = base[1];          // t1 garbage if n==1 (unused)
    int m = 0;
    for (; m + 2 <= n; m += 2) {
        float4 u0 = base[m + 2], u1 = base[m + 3];   // preload next (padded, safe)
        float y0 = fmaf(t0.x, A0, fmaf(t0.y, A1, fmaf(t0.z, A2, t0.w * A3)));
        float y1 = fmaf(t1.x, A0, fmaf(t1.y, A1, fmaf(t1.z, A2, t1.w * A3)));
        vmax = max3f(vmax, y0, y1);
        vmin = min3f(vmin, y0, y1);
        t0 = u0; t1 = u1;
    }
    if (m < n) {
        float y = fmaf(t0.x, A0, fmaf(t0.y, A1, fmaf(t0.z, A2, t0.w * A3)));
        vmax = fmaxf(vmax, y);
        vmin = fminf(vmin, y);
    }
    dmax = vmax; dmin = vmin;
}

__global__ __launch_bounds__(256) void pfn_kernel(
    const float* __restrict__ features,   // (N, 32, 4)
    const int*   __restrict__ num_points, // (N,)
    const int*   __restrict__ coors,      // (N, 4)
    const float* __restrict__ W,          // (64, 10)
    const float* __restrict__ gamma,      // (64,)
    const float* __restrict__ beta,       // (64,)
    const float* __restrict__ rmean,      // (64,)
    const float* __restrict__ rvar,      // (64,)
    float*       __restrict__ out,        // (N, 64)
    int nTotal)
{
    // 4 waves x 2 pairs x 64 float4 = 512 slots + preload pad
    __shared__ float4 lds[520];

    const int lane = threadIdx.x & 63;
    const int wid  = threadIdx.x >> 6;
    const int wv   = blockIdx.x * 4 + wid;
    const int nPairs = (nTotal + 1) >> 1;
    const int p0 = wv * 2;
    if (p0 >= nPairs) return;
    const int p1 = (p0 + 1 < nPairs) ? (p0 + 1) : p0;   // clamp: duplicate work, benign

    // ---- issue both 1KB feature loads up front (latency overlaps everything below) ----
    const float4* fbase = reinterpret_cast<const float4*>(features);
    const float4 f0 = fbase[(size_t)p0 * 64 + lane];
    const float4 f1 = fbase[(size_t)p1 * 64 + lane];

    const int i0A = 2 * p0;
    const bool h0B = (2 * p0 + 1 < nTotal);
    const int i0B = h0B ? (2 * p0 + 1) : (nTotal - 1);
    const int i1A = 2 * p1;
    const bool h1B = (2 * p1 + 1 < nTotal);
    const int i1B = h1B ? (2 * p1 + 1) : (nTotal - 1);

    const int n0A = num_points[i0A], n0B = num_points[i0B];
    const int n1A = num_points[i1A], n1B = num_points[i1B];
    const int4 c0A = reinterpret_cast<const int4*>(coors)[i0A];
    const int4 c0B = reinterpret_cast<const int4*>(coors)[i0B];
    const int4 c1A = reinterpret_cast<const int4*>(coors)[i1A];
    const int4 c1B = reinterpret_cast<const int4*>(coors)[i1B];

    // lane == output channel o
    const int o = lane;
    const float w0 = W[o*10+0], w1 = W[o*10+1], w2 = W[o*10+2], w3 = W[o*10+3],
                w4 = W[o*10+4], w5 = W[o*10+5], w6 = W[o*10+6], w7 = W[o*10+7],
                w8 = W[o*10+8], w9 = W[o*10+9];
    const float a = gamma[o] / sqrtf(rvar[o] + 1e-3f);
    const float b = fmaf(-rmean[o], a, beta[o]);
    const float A0 = a*(w0+w4+w7), A1 = a*(w1+w5+w8), A2 = a*(w2+w6+w9), A3 = a*w3;

    // ---- LDS stage (per-wave 2KB: pair0 at +0, pair1 at +64) ----
    float4* slot = &lds[wid * 128];
    slot[lane]      = f0;
    slot[64 + lane] = f1;

    // ---- DPP half-wave sums (off critical path thanks to C-deferral) ----
    float s0Ax, s0Bx, s0Ay, s0By, s0Az, s0Bz;
    float s1Ax, s1Bx, s1Ay, s1By, s1Az, s1Bz;
    half_sums(f0.x, s0Ax, s0Bx);
    half_sums(f0.y, s0Ay, s0By);
    half_sums(f0.z, s0Az, s0Bz);
    half_sums(f1.x, s1Ax, s1Bx);
    half_sums(f1.y, s1Ay, s1By);
    half_sums(f1.z, s1Az, s1Bz);

    // means via v_rcp (<=1ulp), voxel-center offsets, K, C  (x4 pillars)
    const float rc0A = __builtin_amdgcn_rcpf((float)n0A);
    const float rc0B = __builtin_amdgcn_rcpf((float)n0B);
    const float rc1A = __builtin_amdgcn_rcpf((float)n1A);
    const float rc1B = __builtin_amdgcn_rcpf((float)n1B);

    const float K0A = -((s0Ax*rc0A)*w4 + (s0Ay*rc0A)*w5 + (s0Az*rc0A)*w6
                      + fmaf((float)c0A.z, 0.2f, 0.1f)*w7
                      + fmaf((float)c0A.y, 0.2f, -39.9f)*w8
                      + fmaf((float)c0A.x, 4.0f, -1.0f)*w9);
    const float K0B = -((s0Bx*rc0B)*w4 + (s0By*rc0B)*w5 + (s0Bz*rc0B)*w6
                      + fmaf((float)c0B.z, 0.2f, 0.1f)*w7
                      + fmaf((float)c0B.y, 0.2f, -39.9f)*w8
                      + fmaf((float)c0B.x, 4.0f, -1.0f)*w9);
    const float K1A = -((s1Ax*rc1A)*w4 + (s1Ay*rc1A)*w5 + (s1Az*rc1A)*w6
                      + fmaf((float)c1A.z, 0.2f, 0.1f)*w7
                      + fmaf((float)c1A.y, 0.2f, -39.9f)*w8
                      + fmaf((float)c1A.x, 4.0f, -1.0f)*w9);
    const float K1B = -((s1Bx*rc1B)*w4 + (s1By*rc1B)*w5 + (s1Bz*rc1B)*w6
                      + fmaf((float)c1B.z, 0.2f, 0.1f)*w7
                      + fmaf((float)c1B.y, 0.2f, -39.9f)*w8
                      + fmaf((float)c1B.x, 4.0f, -1.0f)*w9);
    const float C0A = fmaf(a, K0A, b), C0B = fmaf(a, K0B, b);
    const float C1A = fmaf(a, K1A, b), C1B = fmaf(a, K1B, b);

    // compiler-only fence: keep scan reads after the LDS writes (HW DS pipe is in-order
    // per wave, so no lgkmcnt drain needed for the same-wave RAW).
    asm volatile("" ::: "memory");

    // ---- C-deferred scans (n is wave-uniform; depth-1 preloaded) ----
    float d0Amax, d0Amin, d0Bmax, d0Bmin, d1Amax, d1Amin, d1Bmax, d1Bmin;
    scan_minmax(slot,      n0A, A0, A1, A2, A3, d0Amax, d0Amin);
    scan_minmax(slot + 32, n0B, A0, A1, A2, A3, d0Bmax, d0Bmin);
    scan_minmax(slot + 64, n1A, A0, A1, A2, A3, d1Amax, d1Amin);
    scan_minmax(slot + 96, n1B, A0, A1, A2, A3, d1Bmax, d1Bmin);

    float vmax0A = d0Amax + C0A, vmin0A = d0Amin + C0A;
    float vmax0B = d0Bmax + C0B, vmin0B = d0Bmin + C0B;
    float vmax1A = d1Amax + C1A, vmin1A = d1Amin + C1A;
    float vmax1B = d1Bmax + C1B, vmin1B = d1Bmin + C1B;

    if (n0A < 32) { vmax0A = fmaxf(vmax0A, b); vmin0A = fminf(vmin0A, b); }
    if (n0B < 32) { vmax0B = fmaxf(vmax0B, b); vmin0B = fminf(vmin0B, b); }
    if (n1A < 32) { vmax1A = fmaxf(vmax1A, b); vmin1A = fminf(vmin1A, b); }
    if (n1B < 32) { vmax1B = fmaxf(vmax1B, b); vmin1B = fminf(vmin1B, b); }

    // valley property + packed branchless gelu (4 independent evals: good ILP)
    const f32x2 g0A = gelu2((f32x2){vmax0A, vmin0A});
    const f32x2 g0B = gelu2((f32x2){vmax0B, vmin0B});
    const f32x2 g1A = gelu2((f32x2){vmax1A, vmin1A});
    const f32x2 g1B = gelu2((f32x2){vmax1B, vmin1B});

    out[(size_t)i0A * 64 + o] = fmaxf(g0A.x, g0A.y);
    if (h0B) out[(size_t)i0B * 64 + o] = fmaxf(g0B.x, g0B.y);
    out[(size_t)i1A * 64 + o] = fmaxf(g1A.x, g1A.y);
    if (h1B) out[(size_t)i1B * 64 + o] = fmaxf(g1B.x, g1B.y);
}

extern "C" void kernel_launch(void* const* d_in, const int* in_sizes, int n_in,
                              void* d_out, int out_size, void* d_ws, size_t ws_size,
                              hipStream_t stream) {
    const float* features   = (const float*)d_in[0];
    const int*   num_points = (const int*)  d_in[1];
    const int*   coors      = (const int*)  d_in[2];
    const float* W          = (const float*)d_in[3];
    const float* gamma      = (const float*)d_in[4];
    const float* beta       = (const float*)d_in[5];
    const float* rmean      = (const float*)d_in[6];
    const float* rvar       = (const float*)d_in[7];
    float* out = (float*)d_out;

    const int nTotal = in_sizes[1];  // N pillars

    // 4 waves x 2 consecutive pairs per wave = 8 pairs/block
    const int nPairs = (nTotal + 1) / 2;
    int blocks = (nPairs + 7) / 8;
    if (blocks < 1) blocks = 1;
    pfn_kernel<<<blocks, 256, 0, stream>>>(features, num_points, coors, W,
                                           gamma, beta, rmean, rvar, out, nTotal);
}